// Round 1
// 6141.525 us; speedup vs baseline: 1.1007x; 1.1007x over previous
//
#include <hip/hip_runtime.h>

#define NEGV -1e30f

__device__ __forceinline__ float4 ld4(const float* p) {
  return *reinterpret_cast<const float4*>(p);
}

__device__ __forceinline__ void fma8(float (&acc)[8], float4 w0, float4 w1, float a) {
  acc[0] = fmaf(a, w0.x, acc[0]);
  acc[1] = fmaf(a, w0.y, acc[1]);
  acc[2] = fmaf(a, w0.z, acc[2]);
  acc[3] = fmaf(a, w0.w, acc[3]);
  acc[4] = fmaf(a, w1.x, acc[4]);
  acc[5] = fmaf(a, w1.y, acc[5]);
  acc[6] = fmaf(a, w1.z, acc[6]);
  acc[7] = fmaf(a, w1.w, acc[7]);
}

// 4 waves (256 threads) per sample. Rows split 8/wave (h[8], lane = channel).
// All 8 heads computed at once (half-wave slot = head). LDS:
//   aT[64][32]  : LN output, channel-major (aT[d][r])
//   B1[64][32]  : kT (attention) / m1T (MLP chunk)
//   B2[64][32]  : vT, then oT after a barrier (aliased)
// Stride 32 (no pad): reads are row-contiguous or broadcast; transposed float4
// writes sit at the b128 write-phase floor regardless of padding.
__launch_bounds__(256, 6)
__global__ void dwf_kernel(
    const float* __restrict__ x,
    const float* __restrict__ tok_emb,
    const float* __restrict__ pos_emb,
    const float* __restrict__ ln1_g, const float* __restrict__ ln1_b,
    const float* __restrict__ wqkv,  const float* __restrict__ bqkv,
    const float* __restrict__ wo,    const float* __restrict__ bo,
    const float* __restrict__ ln2_g, const float* __restrict__ ln2_b,
    const float* __restrict__ w1,    const float* __restrict__ b1,
    const float* __restrict__ w2,    const float* __restrict__ b2,
    const float* __restrict__ lnf_g, const float* __restrict__ lnf_b,
    const float* __restrict__ w_out, const float* __restrict__ b_out,
    const float* __restrict__ wp1,   const float* __restrict__ bp1,
    const float* __restrict__ wp2,   const float* __restrict__ bp2,
    const float* __restrict__ wp3,   const float* __restrict__ bp3,
    float* __restrict__ out, int out_pairs)
{
  const int s    = blockIdx.x;
  const int tid  = threadIdx.x;
  const int w    = tid >> 6;        // wave 0..3 (owns rows 8w..8w+7)
  const int lane = tid & 63;        // channel
  const int i32  = tid & 31;        // row (attention)
  const int hh   = tid >> 5;        // head 0..7 (half-wave slot)
  const int g    = (tid >> 5) & 1;  // logit-column selector (wave 0 head phase)

  __shared__ float aT[64 * 32];
  __shared__ float B1[64 * 32];
  __shared__ float B2[64 * 32];
  __shared__ float xs[64];
  __shared__ float phb[64];
  __shared__ int   pis[32];
  __shared__ int   toks[32];

  const float* xrow = x + s * 64;
  if (tid < 64) xs[tid] = xrow[tid];

  unsigned long long umask = 0ull, dmask = 0ull;
  if (w == 0) {
    int ubit = 0, dbit = 0;
    if (lane < 32) {
      ubit = xrow[2 * i32]     > 0.f;
      dbit = xrow[2 * i32 + 1] > 0.f;
    }
    umask = __ballot(ubit);   // lanes>=32 contribute 0
    dmask = __ballot(dbit);
    int pi   = ubit + 2 * dbit;
    int prev = __shfl_up(pi, 1);
    if (lane < 32) {
      pis[i32]  = pi;
      toks[i32] = (i32 == 0) ? 4 : prev;
    }
  }
  __syncthreads();

  // h[q] = h[row 8w+q][channel lane]
  float h[8];
  #pragma unroll
  for (int q = 0; q < 8; ++q) {
    int r = 8 * w + q;
    h[q] = tok_emb[toks[r] * 64 + lane] + pos_emb[r * 64 + lane];
  }

  auto layernorm = [&](const float* gp, const float* bp) {
    float gv = gp[lane], bv = bp[lane];
    float vals[8];
    #pragma unroll
    for (int q = 0; q < 8; ++q) {
      float sm = h[q], sq = h[q] * h[q];
      #pragma unroll
      for (int off = 32; off; off >>= 1) {
        sm += __shfl_xor(sm, off);
        sq += __shfl_xor(sq, off);
      }
      float mean = sm * 0.015625f;
      float var  = fmaf(-mean, mean, sq * 0.015625f);
      float rs   = rsqrtf(var + 1e-5f);
      vals[q] = fmaf((h[q] - mean) * rs, gv, bv);
    }
    *reinterpret_cast<float4*>(&aT[lane * 32 + 8 * w]) =
        make_float4(vals[0], vals[1], vals[2], vals[3]);
    *reinterpret_cast<float4*>(&aT[lane * 32 + 8 * w + 4]) =
        make_float4(vals[4], vals[5], vals[6], vals[7]);
  };

  for (int l = 0; l < 6; ++l) {
    // ---------------- attention ----------------
    layernorm(ln1_g + l * 64, ln1_b + l * 64);
    __syncthreads();

    const float* wl = wqkv + l * 64 * 192;
    const float* bq = bqkv + l * 192;
    float qa[8], ka[8], va[8];
    #pragma unroll
    for (int e = 0; e < 8; ++e) {
      qa[e] = bq[8 * hh + e];
      ka[e] = bq[64 + 8 * hh + e];
      va[e] = bq[128 + 8 * hh + e];
    }
    // q,k,v GEMM for rows=i32, head hh (K=64)
    #pragma unroll 2
    for (int d = 0; d < 64; ++d) {
      float av = aT[d * 32 + i32];
      const float* wr = wl + d * 192 + 8 * hh;
      float4 q0 = ld4(wr);        float4 q1 = ld4(wr + 4);
      float4 k0 = ld4(wr + 64);   float4 k1 = ld4(wr + 68);
      float4 v0 = ld4(wr + 128);  float4 v1 = ld4(wr + 132);
      fma8(qa, q0, q1, av);
      fma8(ka, k0, k1, av);
      fma8(va, v0, v1, av);
    }
    #pragma unroll
    for (int e = 0; e < 8; ++e) {
      B1[(8 * hh + e) * 32 + i32] = ka[e];   // kT
      B2[(8 * hh + e) * 32 + i32] = va[e];   // vT
    }
    __syncthreads();

    // scores p[j] = q . k_j
    float p[32];
    #pragma unroll
    for (int j4 = 0; j4 < 8; ++j4) {
      float a0 = 0.f, a1 = 0.f, a2 = 0.f, a3 = 0.f;
      #pragma unroll
      for (int c = 0; c < 8; ++c) {
        float4 kv = *reinterpret_cast<const float4*>(&B1[(8 * hh + c) * 32 + 4 * j4]);
        a0 = fmaf(qa[c], kv.x, a0);
        a1 = fmaf(qa[c], kv.y, a1);
        a2 = fmaf(qa[c], kv.z, a2);
        a3 = fmaf(qa[c], kv.w, a3);
      }
      p[4 * j4]     = a0;
      p[4 * j4 + 1] = a1;
      p[4 * j4 + 2] = a2;
      p[4 * j4 + 3] = a3;
    }
    // causal softmax over j<=i32, scale 1/sqrt(8)
    float mx = NEGV;
    #pragma unroll
    for (int j = 0; j < 32; ++j) {
      p[j] = (j <= i32) ? p[j] * 0.35355339059327373f : NEGV;
      mx = fmaxf(mx, p[j]);
    }
    float sum = 0.f;
    #pragma unroll
    for (int j = 0; j < 32; ++j) {
      p[j] = __expf(p[j] - mx);
      sum += p[j];
    }
    float inv = 1.0f / sum;
    #pragma unroll
    for (int j = 0; j < 32; ++j) p[j] *= inv;

    // o[e] = sum_j p[j]*v[j][e]
    float oa[8];
    #pragma unroll
    for (int e = 0; e < 8; ++e) {
      float acc = 0.f;
      #pragma unroll
      for (int j4 = 0; j4 < 8; ++j4) {
        float4 vv = *reinterpret_cast<const float4*>(&B2[(8 * hh + e) * 32 + 4 * j4]);
        acc = fmaf(p[4 * j4],     vv.x, acc);
        acc = fmaf(p[4 * j4 + 1], vv.y, acc);
        acc = fmaf(p[4 * j4 + 2], vv.z, acc);
        acc = fmaf(p[4 * j4 + 3], vv.w, acc);
      }
      oa[e] = acc;
    }
    __syncthreads();   // all kT/vT reads done
    #pragma unroll
    for (int e = 0; e < 8; ++e) B2[(8 * hh + e) * 32 + i32] = oa[e];  // oT over vT
    __syncthreads();

    // h[r][lane] += sum_d oT[d][r] * wo[d][lane]  (own 8 rows)
    const float* wop = wo + l * 4096 + lane;
    #pragma unroll 2
    for (int d = 0; d < 64; ++d) {
      float wv = wop[d * 64];
      float4 o0 = *reinterpret_cast<const float4*>(&B2[d * 32 + 8 * w]);
      float4 o1 = *reinterpret_cast<const float4*>(&B2[d * 32 + 8 * w + 4]);
      h[0] = fmaf(wv, o0.x, h[0]);
      h[1] = fmaf(wv, o0.y, h[1]);
      h[2] = fmaf(wv, o0.z, h[2]);
      h[3] = fmaf(wv, o0.w, h[3]);
      h[4] = fmaf(wv, o1.x, h[4]);
      h[5] = fmaf(wv, o1.y, h[5]);
      h[6] = fmaf(wv, o1.z, h[6]);
      h[7] = fmaf(wv, o1.w, h[7]);
    }
    {
      float bov = bo[l * 64 + lane];
      #pragma unroll
      for (int q = 0; q < 8; ++q) h[q] += bov;
    }

    // ---------------- MLP ----------------
    layernorm(ln2_g + l * 64, ln2_b + l * 64);
    __syncthreads();
    const float* w1base = w1 + l * 64 * 256;
    const float* w2base = w2 + l * 256 * 64;
    for (int cc = 0; cc < 4; ++cc) {
      float b1v = b1[l * 256 + cc * 64 + lane];
      float macc[8];
      #pragma unroll
      for (int q = 0; q < 8; ++q) macc[q] = b1v;
      const float* w1p = w1base + cc * 64 + lane;
      #pragma unroll 2
      for (int d = 0; d < 64; ++d) {
        float wv = w1p[d * 256];
        float4 a0 = *reinterpret_cast<const float4*>(&aT[d * 32 + 8 * w]);
        float4 a1 = *reinterpret_cast<const float4*>(&aT[d * 32 + 8 * w + 4]);
        macc[0] = fmaf(wv, a0.x, macc[0]);
        macc[1] = fmaf(wv, a0.y, macc[1]);
        macc[2] = fmaf(wv, a0.z, macc[2]);
        macc[3] = fmaf(wv, a0.w, macc[3]);
        macc[4] = fmaf(wv, a1.x, macc[4]);
        macc[5] = fmaf(wv, a1.y, macc[5]);
        macc[6] = fmaf(wv, a1.z, macc[6]);
        macc[7] = fmaf(wv, a1.w, macc[7]);
      }
      __syncthreads();   // previous chunk's m1T reads done
      *reinterpret_cast<float4*>(&B1[lane * 32 + 8 * w]) =
          make_float4(fmaxf(macc[0], 0.f), fmaxf(macc[1], 0.f),
                      fmaxf(macc[2], 0.f), fmaxf(macc[3], 0.f));
      *reinterpret_cast<float4*>(&B1[lane * 32 + 8 * w + 4]) =
          make_float4(fmaxf(macc[4], 0.f), fmaxf(macc[5], 0.f),
                      fmaxf(macc[6], 0.f), fmaxf(macc[7], 0.f));
      __syncthreads();
      const float* w2p = w2base + cc * 64 * 64 + lane;
      #pragma unroll 2
      for (int dc = 0; dc < 64; ++dc) {
        float wv = w2p[dc * 64];
        float4 m0  = *reinterpret_cast<const float4*>(&B1[dc * 32 + 8 * w]);
        float4 m1v = *reinterpret_cast<const float4*>(&B1[dc * 32 + 8 * w + 4]);
        h[0] = fmaf(wv, m0.x,  h[0]);
        h[1] = fmaf(wv, m0.y,  h[1]);
        h[2] = fmaf(wv, m0.z,  h[2]);
        h[3] = fmaf(wv, m0.w,  h[3]);
        h[4] = fmaf(wv, m1v.x, h[4]);
        h[5] = fmaf(wv, m1v.y, h[5]);
        h[6] = fmaf(wv, m1v.z, h[6]);
        h[7] = fmaf(wv, m1v.w, h[7]);
      }
    }
    {
      float b2v = b2[l * 64 + lane];
      #pragma unroll
      for (int q = 0; q < 8; ++q) h[q] += b2v;
    }
  }

  // ---------------- head: logits + masked log_softmax (wave 0) ----------------
  layernorm(lnf_g, lnf_b);
  __syncthreads();

  float amps = 0.f;
  if (w == 0) {
    float la = b_out[2 * g], lb = b_out[2 * g + 1];
    #pragma unroll 4
    for (int d = 0; d < 64; ++d) {
      float av = aT[d * 32 + i32];
      la = fmaf(av, w_out[d * 4 + 2 * g],     la);
      lb = fmaf(av, w_out[d * 4 + 2 * g + 1], lb);
    }
    float lc  = __shfl_xor(la, 32);
    float ldt = __shfl_xor(lb, 32);

    int r   = i32;
    int nup = __popcll(umask & ((1ull << r) - 1ull));
    int ndn = __popcll(dmask & ((1ull << r) - 1ull));
    int rem = 31 - r;
    float lg[4] = {la, lb, lc, ldt};   // valid on lanes<32 (g=0)
    float ml[4];
    #pragma unroll
    for (int c = 0; c < 4; ++c) {
      int nu = nup + (c & 1);
      int nd = ndn + (c >> 1);
      bool ok = (nu <= 16) && (nd <= 16) && (16 - nu <= rem) && (16 - nd <= rem);
      ml[c] = ok ? lg[c] : NEGV;
    }
    float m4 = fmaxf(fmaxf(ml[0], ml[1]), fmaxf(ml[2], ml[3]));
    float se = __expf(ml[0] - m4) + __expf(ml[1] - m4) +
               __expf(ml[2] - m4) + __expf(ml[3] - m4);
    int c = pis[r];
    float mls = (c == 0) ? ml[0] : (c == 1) ? ml[1] : (c == 2) ? ml[2] : ml[3];
    float amp_part = (lane < 32) ? (mls - m4 - __logf(se)) : 0.f;
    amps = amp_part;
    #pragma unroll
    for (int off = 32; off; off >>= 1) amps += __shfl_xor(amps, off);
  }

  // ---------------- phase MLP (all waves, redundant/identical) ----------------
  float p1 = bp1[lane];
  #pragma unroll 4
  for (int d = 0; d < 64; ++d)
    p1 = fmaf(xs[d], wp1[d * 64 + lane], p1);
  p1 = fmaxf(p1, 0.f);
  phb[lane] = p1;   // identical values from all 4 waves
  __syncthreads();
  float p2 = bp2[lane];
  #pragma unroll 4
  for (int d = 0; d < 64; ++d)
    p2 = fmaf(phb[d], wp2[d * 64 + lane], p2);
  p2 = fmaxf(p2, 0.f);
  float p3 = p2 * wp3[lane];
  #pragma unroll
  for (int off = 32; off; off >>= 1) p3 += __shfl_xor(p3, off);
  float ph = p3 + bp3[0];

  if (tid == 0) {
    float amp = expf(0.5f * amps);
    if (out_pairs) {
      out[2 * s]     = amp * cosf(ph);
      out[2 * s + 1] = amp * sinf(ph);
    } else {
      // harness flattened complex64 via astype(float32): real part only
      out[s] = amp * cosf(ph);
    }
  }
}

extern "C" void kernel_launch(void* const* d_in, const int* in_sizes, int n_in,
                              void* d_out, int out_size, void* d_ws, size_t ws_size,
                              hipStream_t stream) {
  (void)n_in; (void)d_ws; (void)ws_size;
  const int B = in_sizes[0] / 64;
  const int out_pairs = (out_size >= 2 * B) ? 1 : 0;
  dwf_kernel<<<B, 256, 0, stream>>>(
      (const float*)d_in[0],  (const float*)d_in[1],  (const float*)d_in[2],
      (const float*)d_in[3],  (const float*)d_in[4],  (const float*)d_in[5],
      (const float*)d_in[6],  (const float*)d_in[7],  (const float*)d_in[8],
      (const float*)d_in[9],  (const float*)d_in[10], (const float*)d_in[11],
      (const float*)d_in[12], (const float*)d_in[13], (const float*)d_in[14],
      (const float*)d_in[15], (const float*)d_in[16], (const float*)d_in[17],
      (const float*)d_in[18], (const float*)d_in[19], (const float*)d_in[20],
      (const float*)d_in[21], (const float*)d_in[22], (const float*)d_in[23],
      (const float*)d_in[24], (float*)d_out, out_pairs);
}

// Round 2
// 4938.589 us; speedup vs baseline: 1.3688x; 1.2436x over previous
//
#include <hip/hip_runtime.h>

#define NEGV -1e30f
#define STR 36   // LDS row stride (floats): 36 = 16B-aligned + bank-uniform

__device__ __forceinline__ float4 ld4(const float* p) {
  return *reinterpret_cast<const float4*>(p);
}

__device__ __forceinline__ void fma8(float (&acc)[8], float4 w0, float4 w1, float a) {
  acc[0] = fmaf(a, w0.x, acc[0]);
  acc[1] = fmaf(a, w0.y, acc[1]);
  acc[2] = fmaf(a, w0.z, acc[2]);
  acc[3] = fmaf(a, w0.w, acc[3]);
  acc[4] = fmaf(a, w1.x, acc[4]);
  acc[5] = fmaf(a, w1.y, acc[5]);
  acc[6] = fmaf(a, w1.z, acc[6]);
  acc[7] = fmaf(a, w1.w, acc[7]);
}

// 4 waves (256 threads) per sample. Rows split 8/wave (h[8], lane = channel).
// All 8 heads computed at once (half-wave slot = head). LDS rows padded to
// stride 36: transposed float4 writes spread over all 32 banks (stride 32 put
// every lane on banks 0-3 -> 136M conflict cycles, measured).
// __launch_bounds__(256,4): 128-VGPR budget -- the live set (p[32]+qkv accs+
// in-flight loads) needs ~100; the previous (256,6)=85 cap spilled to scratch
// (1.2 GB WRITE_SIZE, 950 MB FETCH_SIZE, measured).
__launch_bounds__(256, 4)
__global__ void dwf_kernel(
    const float* __restrict__ x,
    const float* __restrict__ tok_emb,
    const float* __restrict__ pos_emb,
    const float* __restrict__ ln1_g, const float* __restrict__ ln1_b,
    const float* __restrict__ wqkv,  const float* __restrict__ bqkv,
    const float* __restrict__ wo,    const float* __restrict__ bo,
    const float* __restrict__ ln2_g, const float* __restrict__ ln2_b,
    const float* __restrict__ w1,    const float* __restrict__ b1,
    const float* __restrict__ w2,    const float* __restrict__ b2,
    const float* __restrict__ lnf_g, const float* __restrict__ lnf_b,
    const float* __restrict__ w_out, const float* __restrict__ b_out,
    const float* __restrict__ wp1,   const float* __restrict__ bp1,
    const float* __restrict__ wp2,   const float* __restrict__ bp2,
    const float* __restrict__ wp3,   const float* __restrict__ bp3,
    float* __restrict__ out, int out_pairs)
{
  const int s    = blockIdx.x;
  const int tid  = threadIdx.x;
  const int w    = tid >> 6;        // wave 0..3 (owns rows 8w..8w+7)
  const int lane = tid & 63;        // channel
  const int i32  = tid & 31;        // row (attention)
  const int hh   = tid >> 5;        // head 0..7 (half-wave slot)
  const int g    = (tid >> 5) & 1;  // logit-column selector (wave 0 head phase)

  __shared__ float aT[64 * STR];
  __shared__ float B1[64 * STR];
  __shared__ float B2[64 * STR];
  __shared__ float xs[64];
  __shared__ float phb[64];
  __shared__ int   pis[32];
  __shared__ int   toks[32];

  const float* xrow = x + s * 64;
  if (tid < 64) xs[tid] = xrow[tid];

  unsigned long long umask = 0ull, dmask = 0ull;
  if (w == 0) {
    int ubit = 0, dbit = 0;
    if (lane < 32) {
      ubit = xrow[2 * i32]     > 0.f;
      dbit = xrow[2 * i32 + 1] > 0.f;
    }
    umask = __ballot(ubit);   // lanes>=32 contribute 0
    dmask = __ballot(dbit);
    int pi   = ubit + 2 * dbit;
    int prev = __shfl_up(pi, 1);
    if (lane < 32) {
      pis[i32]  = pi;
      toks[i32] = (i32 == 0) ? 4 : prev;
    }
  }
  __syncthreads();

  // h[q] = h[row 8w+q][channel lane]
  float h[8];
  #pragma unroll
  for (int q = 0; q < 8; ++q) {
    int r = 8 * w + q;
    h[q] = tok_emb[toks[r] * 64 + lane] + pos_emb[r * 64 + lane];
  }

  auto layernorm = [&](const float* gp, const float* bp) {
    float gv = gp[lane], bv = bp[lane];
    float vals[8];
    #pragma unroll
    for (int q = 0; q < 8; ++q) {
      float sm = h[q], sq = h[q] * h[q];
      #pragma unroll
      for (int off = 32; off; off >>= 1) {
        sm += __shfl_xor(sm, off);
        sq += __shfl_xor(sq, off);
      }
      float mean = sm * 0.015625f;
      float var  = fmaf(-mean, mean, sq * 0.015625f);
      float rs   = rsqrtf(var + 1e-5f);
      vals[q] = fmaf((h[q] - mean) * rs, gv, bv);
    }
    *reinterpret_cast<float4*>(&aT[lane * STR + 8 * w]) =
        make_float4(vals[0], vals[1], vals[2], vals[3]);
    *reinterpret_cast<float4*>(&aT[lane * STR + 8 * w + 4]) =
        make_float4(vals[4], vals[5], vals[6], vals[7]);
  };

  for (int l = 0; l < 6; ++l) {
    // ---------------- attention ----------------
    layernorm(ln1_g + l * 64, ln1_b + l * 64);
    __syncthreads();

    const float* wl = wqkv + l * 64 * 192;
    const float* bq = bqkv + l * 192;
    float qa[8], ka[8], va[8];
    #pragma unroll
    for (int e = 0; e < 8; ++e) {
      qa[e] = bq[8 * hh + e];
      ka[e] = bq[64 + 8 * hh + e];
      va[e] = bq[128 + 8 * hh + e];
    }
    // q,k,v GEMM for rows=i32, head hh (K=64)
    #pragma unroll 2
    for (int d = 0; d < 64; ++d) {
      float av = aT[d * STR + i32];
      const float* wr = wl + d * 192 + 8 * hh;
      float4 q0 = ld4(wr);        float4 q1 = ld4(wr + 4);
      float4 k0 = ld4(wr + 64);   float4 k1 = ld4(wr + 68);
      float4 v0 = ld4(wr + 128);  float4 v1 = ld4(wr + 132);
      fma8(qa, q0, q1, av);
      fma8(ka, k0, k1, av);
      fma8(va, v0, v1, av);
    }
    #pragma unroll
    for (int e = 0; e < 8; ++e) {
      B1[(8 * hh + e) * STR + i32] = ka[e];   // kT
      B2[(8 * hh + e) * STR + i32] = va[e];   // vT
    }
    __syncthreads();

    // scores p[j] = q . k_j
    float p[32];
    #pragma unroll
    for (int j4 = 0; j4 < 8; ++j4) {
      float a0 = 0.f, a1 = 0.f, a2 = 0.f, a3 = 0.f;
      #pragma unroll
      for (int c = 0; c < 8; ++c) {
        float4 kv = *reinterpret_cast<const float4*>(&B1[(8 * hh + c) * STR + 4 * j4]);
        a0 = fmaf(qa[c], kv.x, a0);
        a1 = fmaf(qa[c], kv.y, a1);
        a2 = fmaf(qa[c], kv.z, a2);
        a3 = fmaf(qa[c], kv.w, a3);
      }
      p[4 * j4]     = a0;
      p[4 * j4 + 1] = a1;
      p[4 * j4 + 2] = a2;
      p[4 * j4 + 3] = a3;
    }
    // causal softmax over j<=i32, scale 1/sqrt(8)
    float mx = NEGV;
    #pragma unroll
    for (int j = 0; j < 32; ++j) {
      p[j] = (j <= i32) ? p[j] * 0.35355339059327373f : NEGV;
      mx = fmaxf(mx, p[j]);
    }
    float sum = 0.f;
    #pragma unroll
    for (int j = 0; j < 32; ++j) {
      p[j] = __expf(p[j] - mx);
      sum += p[j];
    }
    float inv = 1.0f / sum;
    #pragma unroll
    for (int j = 0; j < 32; ++j) p[j] *= inv;

    // o[e] = sum_j p[j]*v[j][e]
    float oa[8];
    #pragma unroll
    for (int e = 0; e < 8; ++e) {
      float acc = 0.f;
      #pragma unroll
      for (int j4 = 0; j4 < 8; ++j4) {
        float4 vv = *reinterpret_cast<const float4*>(&B2[(8 * hh + e) * STR + 4 * j4]);
        acc = fmaf(p[4 * j4],     vv.x, acc);
        acc = fmaf(p[4 * j4 + 1], vv.y, acc);
        acc = fmaf(p[4 * j4 + 2], vv.z, acc);
        acc = fmaf(p[4 * j4 + 3], vv.w, acc);
      }
      oa[e] = acc;
    }
    __syncthreads();   // all kT/vT reads done
    #pragma unroll
    for (int e = 0; e < 8; ++e) B2[(8 * hh + e) * STR + i32] = oa[e];  // oT over vT
    __syncthreads();

    // h[r][lane] += sum_d oT[d][r] * wo[d][lane]  (own 8 rows)
    const float* wop = wo + l * 4096 + lane;
    #pragma unroll 2
    for (int d = 0; d < 64; ++d) {
      float wv = wop[d * 64];
      float4 o0 = *reinterpret_cast<const float4*>(&B2[d * STR + 8 * w]);
      float4 o1 = *reinterpret_cast<const float4*>(&B2[d * STR + 8 * w + 4]);
      h[0] = fmaf(wv, o0.x, h[0]);
      h[1] = fmaf(wv, o0.y, h[1]);
      h[2] = fmaf(wv, o0.z, h[2]);
      h[3] = fmaf(wv, o0.w, h[3]);
      h[4] = fmaf(wv, o1.x, h[4]);
      h[5] = fmaf(wv, o1.y, h[5]);
      h[6] = fmaf(wv, o1.z, h[6]);
      h[7] = fmaf(wv, o1.w, h[7]);
    }
    {
      float bov = bo[l * 64 + lane];
      #pragma unroll
      for (int q = 0; q < 8; ++q) h[q] += bov;
    }

    // ---------------- MLP ----------------
    layernorm(ln2_g + l * 64, ln2_b + l * 64);
    __syncthreads();
    const float* w1base = w1 + l * 64 * 256;
    const float* w2base = w2 + l * 256 * 64;
    for (int cc = 0; cc < 4; ++cc) {
      float b1v = b1[l * 256 + cc * 64 + lane];
      float macc[8];
      #pragma unroll
      for (int q = 0; q < 8; ++q) macc[q] = b1v;
      const float* w1p = w1base + cc * 64 + lane;
      #pragma unroll 2
      for (int d = 0; d < 64; ++d) {
        float wv = w1p[d * 256];
        float4 a0 = *reinterpret_cast<const float4*>(&aT[d * STR + 8 * w]);
        float4 a1 = *reinterpret_cast<const float4*>(&aT[d * STR + 8 * w + 4]);
        macc[0] = fmaf(wv, a0.x, macc[0]);
        macc[1] = fmaf(wv, a0.y, macc[1]);
        macc[2] = fmaf(wv, a0.z, macc[2]);
        macc[3] = fmaf(wv, a0.w, macc[3]);
        macc[4] = fmaf(wv, a1.x, macc[4]);
        macc[5] = fmaf(wv, a1.y, macc[5]);
        macc[6] = fmaf(wv, a1.z, macc[6]);
        macc[7] = fmaf(wv, a1.w, macc[7]);
      }
      __syncthreads();   // previous chunk's m1T reads done
      *reinterpret_cast<float4*>(&B1[lane * STR + 8 * w]) =
          make_float4(fmaxf(macc[0], 0.f), fmaxf(macc[1], 0.f),
                      fmaxf(macc[2], 0.f), fmaxf(macc[3], 0.f));
      *reinterpret_cast<float4*>(&B1[lane * STR + 8 * w + 4]) =
          make_float4(fmaxf(macc[4], 0.f), fmaxf(macc[5], 0.f),
                      fmaxf(macc[6], 0.f), fmaxf(macc[7], 0.f));
      __syncthreads();
      const float* w2p = w2base + cc * 64 * 64 + lane;
      #pragma unroll 2
      for (int dc = 0; dc < 64; ++dc) {
        float wv = w2p[dc * 64];
        float4 m0  = *reinterpret_cast<const float4*>(&B1[dc * STR + 8 * w]);
        float4 m1v = *reinterpret_cast<const float4*>(&B1[dc * STR + 8 * w + 4]);
        h[0] = fmaf(wv, m0.x,  h[0]);
        h[1] = fmaf(wv, m0.y,  h[1]);
        h[2] = fmaf(wv, m0.z,  h[2]);
        h[3] = fmaf(wv, m0.w,  h[3]);
        h[4] = fmaf(wv, m1v.x, h[4]);
        h[5] = fmaf(wv, m1v.y, h[5]);
        h[6] = fmaf(wv, m1v.z, h[6]);
        h[7] = fmaf(wv, m1v.w, h[7]);
      }
    }
    {
      float b2v = b2[l * 64 + lane];
      #pragma unroll
      for (int q = 0; q < 8; ++q) h[q] += b2v;
    }
  }

  // ---------------- head: logits + masked log_softmax (wave 0) ----------------
  layernorm(lnf_g, lnf_b);
  __syncthreads();

  float amps = 0.f;
  if (w == 0) {
    float la = b_out[2 * g], lb = b_out[2 * g + 1];
    #pragma unroll 4
    for (int d = 0; d < 64; ++d) {
      float av = aT[d * STR + i32];
      la = fmaf(av, w_out[d * 4 + 2 * g],     la);
      lb = fmaf(av, w_out[d * 4 + 2 * g + 1], lb);
    }
    float lc  = __shfl_xor(la, 32);
    float ldt = __shfl_xor(lb, 32);

    int r   = i32;
    int nup = __popcll(umask & ((1ull << r) - 1ull));
    int ndn = __popcll(dmask & ((1ull << r) - 1ull));
    int rem = 31 - r;
    float lg[4] = {la, lb, lc, ldt};   // valid on lanes<32 (g=0)
    float ml[4];
    #pragma unroll
    for (int c = 0; c < 4; ++c) {
      int nu = nup + (c & 1);
      int nd = ndn + (c >> 1);
      bool ok = (nu <= 16) && (nd <= 16) && (16 - nu <= rem) && (16 - nd <= rem);
      ml[c] = ok ? lg[c] : NEGV;
    }
    float m4 = fmaxf(fmaxf(ml[0], ml[1]), fmaxf(ml[2], ml[3]));
    float se = __expf(ml[0] - m4) + __expf(ml[1] - m4) +
               __expf(ml[2] - m4) + __expf(ml[3] - m4);
    int c = pis[r];
    float mls = (c == 0) ? ml[0] : (c == 1) ? ml[1] : (c == 2) ? ml[2] : ml[3];
    float amp_part = (lane < 32) ? (mls - m4 - __logf(se)) : 0.f;
    amps = amp_part;
    #pragma unroll
    for (int off = 32; off; off >>= 1) amps += __shfl_xor(amps, off);
  }

  // ---------------- phase MLP (all waves, redundant/identical) ----------------
  float p1 = bp1[lane];
  #pragma unroll 4
  for (int d = 0; d < 64; ++d)
    p1 = fmaf(xs[d], wp1[d * 64 + lane], p1);
  p1 = fmaxf(p1, 0.f);
  phb[lane] = p1;   // identical values from all 4 waves
  __syncthreads();
  float p2 = bp2[lane];
  #pragma unroll 4
  for (int d = 0; d < 64; ++d)
    p2 = fmaf(phb[d], wp2[d * 64 + lane], p2);
  p2 = fmaxf(p2, 0.f);
  float p3 = p2 * wp3[lane];
  #pragma unroll
  for (int off = 32; off; off >>= 1) p3 += __shfl_xor(p3, off);
  float ph = p3 + bp3[0];

  if (tid == 0) {
    float amp = expf(0.5f * amps);
    if (out_pairs) {
      out[2 * s]     = amp * cosf(ph);
      out[2 * s + 1] = amp * sinf(ph);
    } else {
      // harness flattened complex64 via astype(float32): real part only
      out[s] = amp * cosf(ph);
    }
  }
}

extern "C" void kernel_launch(void* const* d_in, const int* in_sizes, int n_in,
                              void* d_out, int out_size, void* d_ws, size_t ws_size,
                              hipStream_t stream) {
  (void)n_in; (void)d_ws; (void)ws_size;
  const int B = in_sizes[0] / 64;
  const int out_pairs = (out_size >= 2 * B) ? 1 : 0;
  dwf_kernel<<<B, 256, 0, stream>>>(
      (const float*)d_in[0],  (const float*)d_in[1],  (const float*)d_in[2],
      (const float*)d_in[3],  (const float*)d_in[4],  (const float*)d_in[5],
      (const float*)d_in[6],  (const float*)d_in[7],  (const float*)d_in[8],
      (const float*)d_in[9],  (const float*)d_in[10], (const float*)d_in[11],
      (const float*)d_in[12], (const float*)d_in[13], (const float*)d_in[14],
      (const float*)d_in[15], (const float*)d_in[16], (const float*)d_in[17],
      (const float*)d_in[18], (const float*)d_in[19], (const float*)d_in[20],
      (const float*)d_in[21], (const float*)d_in[22], (const float*)d_in[23],
      (const float*)d_in[24], (float*)d_out, out_pairs);
}

// Round 3
// 4851.806 us; speedup vs baseline: 1.3933x; 1.0179x over previous
//
#include <hip/hip_runtime.h>

#define NEGV -1e30f
#define STR 36   // LDS row stride (floats): 36 = 16B-aligned + bank-uniform

__device__ __forceinline__ float4 ld4(const float* p) {
  return *reinterpret_cast<const float4*>(p);
}

__device__ __forceinline__ void fma8(float (&acc)[8], float4 w0, float4 w1, float a) {
  acc[0] = fmaf(a, w0.x, acc[0]);
  acc[1] = fmaf(a, w0.y, acc[1]);
  acc[2] = fmaf(a, w0.z, acc[2]);
  acc[3] = fmaf(a, w0.w, acc[3]);
  acc[4] = fmaf(a, w1.x, acc[4]);
  acc[5] = fmaf(a, w1.y, acc[5]);
  acc[6] = fmaf(a, w1.z, acc[6]);
  acc[7] = fmaf(a, w1.w, acc[7]);
}

// 4 waves (256 threads) per sample. Rows split 8/wave (h[8], lane = channel).
// All 8 heads at once (half-wave slot = head).
//
// TWO aliased LDS buffers (was 3) -> 19.5 KB/block -> 8 blocks/CU:
//   SA: aT (LN out) -> [barrier] -> kT -> oT (same-wave overwrite) -> aT(ln2)...
//   SB: vT -> m1T (MLP)
// Hazard analysis: K/V/score/O traffic is within-wave (half-wave = head owns
// its 8 rows; wave-lockstep LDS is in-order) and MLP aT/m1T traffic is
// column-partitioned per wave (wave w owns cols 8w..8w+7). Only 4 barriers
// per layer are cross-wave-required.
__launch_bounds__(256, 4)
__global__ void dwf_kernel(
    const float* __restrict__ x,
    const float* __restrict__ tok_emb,
    const float* __restrict__ pos_emb,
    const float* __restrict__ ln1_g, const float* __restrict__ ln1_b,
    const float* __restrict__ wqkv,  const float* __restrict__ bqkv,
    const float* __restrict__ wo,    const float* __restrict__ bo,
    const float* __restrict__ ln2_g, const float* __restrict__ ln2_b,
    const float* __restrict__ w1,    const float* __restrict__ b1,
    const float* __restrict__ w2,    const float* __restrict__ b2,
    const float* __restrict__ lnf_g, const float* __restrict__ lnf_b,
    const float* __restrict__ w_out, const float* __restrict__ b_out,
    const float* __restrict__ wp1,   const float* __restrict__ bp1,
    const float* __restrict__ wp2,   const float* __restrict__ bp2,
    const float* __restrict__ wp3,   const float* __restrict__ bp3,
    float* __restrict__ out, int out_pairs)
{
  const int s    = blockIdx.x;
  const int tid  = threadIdx.x;
  const int w    = tid >> 6;        // wave 0..3 (owns rows/cols 8w..8w+7)
  const int lane = tid & 63;        // channel
  const int i32  = tid & 31;        // row (attention)
  const int hh   = tid >> 5;        // head 0..7 (half-wave slot)
  const int g    = (tid >> 5) & 1;  // logit-column selector (wave 0 head phase)

  __shared__ float SA[64 * STR];
  __shared__ float SB[64 * STR];
  __shared__ float xs[64];
  __shared__ float phb[64];
  __shared__ int   pis[32];
  __shared__ int   toks[32];

  const float* xrow = x + s * 64;
  if (tid < 64) xs[tid] = xrow[tid];

  unsigned long long umask = 0ull, dmask = 0ull;
  if (w == 0) {
    int ubit = 0, dbit = 0;
    if (lane < 32) {
      ubit = xrow[2 * i32]     > 0.f;
      dbit = xrow[2 * i32 + 1] > 0.f;
    }
    umask = __ballot(ubit);   // lanes>=32 contribute 0
    dmask = __ballot(dbit);
    int pi   = ubit + 2 * dbit;
    int prev = __shfl_up(pi, 1);
    if (lane < 32) {
      pis[i32]  = pi;
      toks[i32] = (i32 == 0) ? 4 : prev;
    }
  }
  __syncthreads();

  // h[q] = h[row 8w+q][channel lane]
  float h[8];
  #pragma unroll
  for (int q = 0; q < 8; ++q) {
    int r = 8 * w + q;
    h[q] = tok_emb[toks[r] * 64 + lane] + pos_emb[r * 64 + lane];
  }

  auto layernorm = [&](const float* gp, const float* bp) {
    float gv = gp[lane], bv = bp[lane];
    float vals[8];
    #pragma unroll
    for (int q = 0; q < 8; ++q) {
      float sm = h[q], sq = h[q] * h[q];
      #pragma unroll
      for (int off = 32; off; off >>= 1) {
        sm += __shfl_xor(sm, off);
        sq += __shfl_xor(sq, off);
      }
      float mean = sm * 0.015625f;
      float var  = fmaf(-mean, mean, sq * 0.015625f);
      float rs   = rsqrtf(var + 1e-5f);
      vals[q] = fmaf((h[q] - mean) * rs, gv, bv);
    }
    *reinterpret_cast<float4*>(&SA[lane * STR + 8 * w]) =
        make_float4(vals[0], vals[1], vals[2], vals[3]);
    *reinterpret_cast<float4*>(&SA[lane * STR + 8 * w + 4]) =
        make_float4(vals[4], vals[5], vals[6], vals[7]);
  };

  for (int l = 0; l < 6; ++l) {
    // ---------------- attention ----------------
    layernorm(ln1_g + l * 64, ln1_b + l * 64);
    __syncthreads();   // (A) aT read cross-wave (col i32 by every wave)

    const float* wl = wqkv + l * 64 * 192;
    const float* bq = bqkv + l * 192;
    float qa[8], ka[8], va[8];
    #pragma unroll
    for (int e = 0; e < 8; ++e) {
      qa[e] = bq[8 * hh + e];
      ka[e] = bq[64 + 8 * hh + e];
      va[e] = bq[128 + 8 * hh + e];
    }
    // q,k,v GEMM for rows=i32, head hh (K=64)
    #pragma unroll 2
    for (int d = 0; d < 64; ++d) {
      float av = SA[d * STR + i32];
      const float* wr = wl + d * 192 + 8 * hh;
      float4 q0 = ld4(wr);        float4 q1 = ld4(wr + 4);
      float4 k0 = ld4(wr + 64);   float4 k1 = ld4(wr + 68);
      float4 v0 = ld4(wr + 128);  float4 v1 = ld4(wr + 132);
      fma8(qa, q0, q1, av);
      fma8(ka, k0, k1, av);
      fma8(va, v0, v1, av);
    }
    // fold softmax scale 1/sqrt(8) into q
    #pragma unroll
    for (int e = 0; e < 8; ++e) qa[e] *= 0.35355339059327373f;

    __syncthreads();   // (B) all aT reads + prev-layer m1T(SB) reads done

    // stage kT->SA (over aT), vT->SB; read back same-wave only
    #pragma unroll
    for (int e = 0; e < 8; ++e) {
      SA[(8 * hh + e) * STR + i32] = ka[e];   // kT
      SB[(8 * hh + e) * STR + i32] = va[e];   // vT
    }

    // scores p[j] = q . k_j  (own head rows; same-wave data)
    float p[32];
    #pragma unroll
    for (int j4 = 0; j4 < 8; ++j4) {
      float a0 = 0.f, a1 = 0.f, a2 = 0.f, a3 = 0.f;
      #pragma unroll
      for (int c = 0; c < 8; ++c) {
        float4 kv = *reinterpret_cast<const float4*>(&SA[(8 * hh + c) * STR + 4 * j4]);
        a0 = fmaf(qa[c], kv.x, a0);
        a1 = fmaf(qa[c], kv.y, a1);
        a2 = fmaf(qa[c], kv.z, a2);
        a3 = fmaf(qa[c], kv.w, a3);
      }
      p[4 * j4]     = a0;
      p[4 * j4 + 1] = a1;
      p[4 * j4 + 2] = a2;
      p[4 * j4 + 3] = a3;
    }
    // causal softmax over j<=i32
    float mx = NEGV;
    #pragma unroll
    for (int j = 0; j < 32; ++j) {
      p[j] = (j <= i32) ? p[j] : NEGV;
      mx = fmaxf(mx, p[j]);
    }
    float sum = 0.f;
    #pragma unroll
    for (int j = 0; j < 32; ++j) {
      p[j] = __expf(p[j] - mx);
      sum += p[j];
    }
    float inv = 1.0f / sum;
    #pragma unroll
    for (int j = 0; j < 32; ++j) p[j] *= inv;

    // o[e] = sum_j p[j]*v[j][e]  (own head rows; same-wave data)
    float oa[8];
    #pragma unroll
    for (int e = 0; e < 8; ++e) {
      float acc = 0.f;
      #pragma unroll
      for (int j4 = 0; j4 < 8; ++j4) {
        float4 vv = *reinterpret_cast<const float4*>(&SB[(8 * hh + e) * STR + 4 * j4]);
        acc = fmaf(p[4 * j4],     vv.x, acc);
        acc = fmaf(p[4 * j4 + 1], vv.y, acc);
        acc = fmaf(p[4 * j4 + 2], vv.z, acc);
        acc = fmaf(p[4 * j4 + 3], vv.w, acc);
      }
      oa[e] = acc;
    }
    // oT -> SA over own head's kT rows (same-wave overwrite, no barrier)
    #pragma unroll
    for (int e = 0; e < 8; ++e) SA[(8 * hh + e) * STR + i32] = oa[e];
    __syncthreads();   // (C) oT read cross-wave next

    // h[r][lane] += sum_d oT[d][r] * wo[d][lane]  (own 8 rows)
    const float* wop = wo + l * 4096 + lane;
    #pragma unroll 2
    for (int d = 0; d < 64; ++d) {
      float wv = wop[d * 64];
      float4 o0 = *reinterpret_cast<const float4*>(&SA[d * STR + 8 * w]);
      float4 o1 = *reinterpret_cast<const float4*>(&SA[d * STR + 8 * w + 4]);
      h[0] = fmaf(wv, o0.x, h[0]);
      h[1] = fmaf(wv, o0.y, h[1]);
      h[2] = fmaf(wv, o0.z, h[2]);
      h[3] = fmaf(wv, o0.w, h[3]);
      h[4] = fmaf(wv, o1.x, h[4]);
      h[5] = fmaf(wv, o1.y, h[5]);
      h[6] = fmaf(wv, o1.z, h[6]);
      h[7] = fmaf(wv, o1.w, h[7]);
    }
    {
      float bov = bo[l * 64 + lane];
      #pragma unroll
      for (int q = 0; q < 8; ++q) h[q] += bov;
    }
    __syncthreads();   // (D) all oT reads done; LN2 overwrites SA

    // ---------------- MLP (no internal barriers: per-wave column traffic) ----
    layernorm(ln2_g + l * 64, ln2_b + l * 64);   // SA cols 8w..8w+7 (own wave)
    const float* w1base = w1 + l * 64 * 256;
    const float* w2base = w2 + l * 256 * 64;
    for (int cc = 0; cc < 4; ++cc) {
      float b1v = b1[l * 256 + cc * 64 + lane];
      float macc[8];
      #pragma unroll
      for (int q = 0; q < 8; ++q) macc[q] = b1v;
      const float* w1p = w1base + cc * 64 + lane;
      #pragma unroll 2
      for (int d = 0; d < 64; ++d) {
        float wv = w1p[d * 256];
        float4 a0 = *reinterpret_cast<const float4*>(&SA[d * STR + 8 * w]);
        float4 a1 = *reinterpret_cast<const float4*>(&SA[d * STR + 8 * w + 4]);
        macc[0] = fmaf(wv, a0.x, macc[0]);
        macc[1] = fmaf(wv, a0.y, macc[1]);
        macc[2] = fmaf(wv, a0.z, macc[2]);
        macc[3] = fmaf(wv, a0.w, macc[3]);
        macc[4] = fmaf(wv, a1.x, macc[4]);
        macc[5] = fmaf(wv, a1.y, macc[5]);
        macc[6] = fmaf(wv, a1.z, macc[6]);
        macc[7] = fmaf(wv, a1.w, macc[7]);
      }
      // m1T -> SB own cols (overwrites vT / prev chunk's m1T: same-wave)
      *reinterpret_cast<float4*>(&SB[lane * STR + 8 * w]) =
          make_float4(fmaxf(macc[0], 0.f), fmaxf(macc[1], 0.f),
                      fmaxf(macc[2], 0.f), fmaxf(macc[3], 0.f));
      *reinterpret_cast<float4*>(&SB[lane * STR + 8 * w + 4]) =
          make_float4(fmaxf(macc[4], 0.f), fmaxf(macc[5], 0.f),
                      fmaxf(macc[6], 0.f), fmaxf(macc[7], 0.f));
      const float* w2p = w2base + cc * 64 * 64 + lane;
      #pragma unroll 2
      for (int dc = 0; dc < 64; ++dc) {
        float wv = w2p[dc * 64];
        float4 m0  = *reinterpret_cast<const float4*>(&SB[dc * STR + 8 * w]);
        float4 m1v = *reinterpret_cast<const float4*>(&SB[dc * STR + 8 * w + 4]);
        h[0] = fmaf(wv, m0.x,  h[0]);
        h[1] = fmaf(wv, m0.y,  h[1]);
        h[2] = fmaf(wv, m0.z,  h[2]);
        h[3] = fmaf(wv, m0.w,  h[3]);
        h[4] = fmaf(wv, m1v.x, h[4]);
        h[5] = fmaf(wv, m1v.y, h[5]);
        h[6] = fmaf(wv, m1v.z, h[6]);
        h[7] = fmaf(wv, m1v.w, h[7]);
      }
    }
    {
      float b2v = b2[l * 64 + lane];
      #pragma unroll
      for (int q = 0; q < 8; ++q) h[q] += b2v;
    }
  }

  // ---------------- head: logits + masked log_softmax (wave 0) ----------------
  layernorm(lnf_g, lnf_b);   // SA own cols (prev readers were own-wave)
  __syncthreads();           // logits read col i32 cross-wave

  float amps = 0.f;
  if (w == 0) {
    float la = b_out[2 * g], lb = b_out[2 * g + 1];
    #pragma unroll 4
    for (int d = 0; d < 64; ++d) {
      float av = SA[d * STR + i32];
      la = fmaf(av, w_out[d * 4 + 2 * g],     la);
      lb = fmaf(av, w_out[d * 4 + 2 * g + 1], lb);
    }
    float lc  = __shfl_xor(la, 32);
    float ldt = __shfl_xor(lb, 32);

    int r   = i32;
    int nup = __popcll(umask & ((1ull << r) - 1ull));
    int ndn = __popcll(dmask & ((1ull << r) - 1ull));
    int rem = 31 - r;
    float lg[4] = {la, lb, lc, ldt};   // valid on lanes<32 (g=0)
    float ml[4];
    #pragma unroll
    for (int c = 0; c < 4; ++c) {
      int nu = nup + (c & 1);
      int nd = ndn + (c >> 1);
      bool ok = (nu <= 16) && (nd <= 16) && (16 - nu <= rem) && (16 - nd <= rem);
      ml[c] = ok ? lg[c] : NEGV;
    }
    float m4 = fmaxf(fmaxf(ml[0], ml[1]), fmaxf(ml[2], ml[3]));
    float se = __expf(ml[0] - m4) + __expf(ml[1] - m4) +
               __expf(ml[2] - m4) + __expf(ml[3] - m4);
    int c = pis[r];
    float mls = (c == 0) ? ml[0] : (c == 1) ? ml[1] : (c == 2) ? ml[2] : ml[3];
    float amp_part = (lane < 32) ? (mls - m4 - __logf(se)) : 0.f;
    amps = amp_part;
    #pragma unroll
    for (int off = 32; off; off >>= 1) amps += __shfl_xor(amps, off);
  }

  // ---------------- phase MLP (all waves, redundant/identical) ----------------
  float p1 = bp1[lane];
  #pragma unroll 4
  for (int d = 0; d < 64; ++d)
    p1 = fmaf(xs[d], wp1[d * 64 + lane], p1);
  p1 = fmaxf(p1, 0.f);
  phb[lane] = p1;   // identical values from all 4 waves (benign race)
  __syncthreads();
  float p2 = bp2[lane];
  #pragma unroll 4
  for (int d = 0; d < 64; ++d)
    p2 = fmaf(phb[d], wp2[d * 64 + lane], p2);
  p2 = fmaxf(p2, 0.f);
  float p3 = p2 * wp3[lane];
  #pragma unroll
  for (int off = 32; off; off >>= 1) p3 += __shfl_xor(p3, off);
  float ph = p3 + bp3[0];

  if (tid == 0) {
    float amp = expf(0.5f * amps);
    if (out_pairs) {
      out[2 * s]     = amp * cosf(ph);
      out[2 * s + 1] = amp * sinf(ph);
    } else {
      // harness flattened complex64 via astype(float32): real part only
      out[s] = amp * cosf(ph);
    }
  }
}

extern "C" void kernel_launch(void* const* d_in, const int* in_sizes, int n_in,
                              void* d_out, int out_size, void* d_ws, size_t ws_size,
                              hipStream_t stream) {
  (void)n_in; (void)d_ws; (void)ws_size;
  const int B = in_sizes[0] / 64;
  const int out_pairs = (out_size >= 2 * B) ? 1 : 0;
  dwf_kernel<<<B, 256, 0, stream>>>(
      (const float*)d_in[0],  (const float*)d_in[1],  (const float*)d_in[2],
      (const float*)d_in[3],  (const float*)d_in[4],  (const float*)d_in[5],
      (const float*)d_in[6],  (const float*)d_in[7],  (const float*)d_in[8],
      (const float*)d_in[9],  (const float*)d_in[10], (const float*)d_in[11],
      (const float*)d_in[12], (const float*)d_in[13], (const float*)d_in[14],
      (const float*)d_in[15], (const float*)d_in[16], (const float*)d_in[17],
      (const float*)d_in[18], (const float*)d_in[19], (const float*)d_in[20],
      (const float*)d_in[21], (const float*)d_in[22], (const float*)d_in[23],
      (const float*)d_in[24], (float*)d_out, out_pairs);
}

// Round 4
// 4032.779 us; speedup vs baseline: 1.6763x; 1.2031x over previous
//
#include <hip/hip_runtime.h>

#define NEGV -1e30f
#define STR 36   // LDS row stride (floats): 16B-aligned + bank-uniform

__device__ __forceinline__ float4 ld4(const float* p) {
  return *reinterpret_cast<const float4*>(p);
}

__device__ __forceinline__ void fma8(float (&acc)[8], float4 w0, float4 w1, float a) {
  acc[0] = fmaf(a, w0.x, acc[0]);
  acc[1] = fmaf(a, w0.y, acc[1]);
  acc[2] = fmaf(a, w0.z, acc[2]);
  acc[3] = fmaf(a, w0.w, acc[3]);
  acc[4] = fmaf(a, w1.x, acc[4]);
  acc[5] = fmaf(a, w1.y, acc[5]);
  acc[6] = fmaf(a, w1.z, acc[6]);
  acc[7] = fmaf(a, w1.w, acc[7]);
}

// 2 samples per block (weight loads amortized 2x), 4 waves of 256 threads.
// Wave w owns rows 8w..8w+7 of BOTH samples (h0[8], h1[8]; lane = channel).
// qkv k/v + wo + MLP run in column-GEMM mode: per d, ONE coalesced weight
// load feeds 16 fma (8 rows x 2 samples); activation LDS reads are
// wave-uniform b128 broadcasts (conflict-free). q stays row-mode with
// half-wave-broadcast weight loads shared across both samples.
// LDS per sample: SA (aT -> kT -> oT), SB (vT -> m1T). 4 tiles = 38 KB ->
// 4 blocks/CU. 4 barriers/layer serve 2 samples.
__launch_bounds__(256, 4)
__global__ void dwf_kernel(
    const float* __restrict__ x,
    const float* __restrict__ tok_emb,
    const float* __restrict__ pos_emb,
    const float* __restrict__ ln1_g, const float* __restrict__ ln1_b,
    const float* __restrict__ wqkv,  const float* __restrict__ bqkv,
    const float* __restrict__ wo,    const float* __restrict__ bo,
    const float* __restrict__ ln2_g, const float* __restrict__ ln2_b,
    const float* __restrict__ w1,    const float* __restrict__ b1,
    const float* __restrict__ w2,    const float* __restrict__ b2,
    const float* __restrict__ lnf_g, const float* __restrict__ lnf_b,
    const float* __restrict__ w_out, const float* __restrict__ b_out,
    const float* __restrict__ wp1,   const float* __restrict__ bp1,
    const float* __restrict__ wp2,   const float* __restrict__ bp2,
    const float* __restrict__ wp3,   const float* __restrict__ bp3,
    float* __restrict__ out, int out_pairs, int nB)
{
  const int s2   = blockIdx.x;      // sample pair index
  const int tid  = threadIdx.x;
  const int w    = tid >> 6;        // wave 0..3 (owns rows 8w..8w+7)
  const int lane = tid & 63;        // channel
  const int i32  = tid & 31;        // row (attention q-assignment)
  const int hh   = tid >> 5;        // head 0..7 (half-wave slot)
  const int g    = (tid >> 5) & 1;  // logit-column selector (per-wave)
  const bool valid1 = (2 * s2 + 1) < nB;

  __shared__ float SA0[64 * STR], SA1[64 * STR];
  __shared__ float SB0[64 * STR], SB1[64 * STR];
  __shared__ float xs[128], phb[128];
  __shared__ int   pis[64], toks[64];

  const float* xbase = x + s2 * 128;
  if (tid < 128) xs[tid] = (tid < 64 || valid1) ? xbase[tid] : 0.f;

  unsigned long long um = 0ull, dm = 0ull;
  if (w < 2) {
    int ub = 0, db = 0;
    if (lane < 32 && (w == 0 || valid1)) {
      const float* xr = xbase + 64 * w;
      ub = xr[2 * i32]     > 0.f;
      db = xr[2 * i32 + 1] > 0.f;
    }
    um = __ballot(ub);   // lanes>=32 contribute 0
    dm = __ballot(db);
    int pi   = ub + 2 * db;
    int prev = __shfl_up(pi, 1);
    if (lane < 32) {
      pis[32 * w + i32]  = pi;
      toks[32 * w + i32] = (i32 == 0) ? 4 : prev;
    }
  }
  __syncthreads();

  float h0[8], h1[8];
  #pragma unroll
  for (int q = 0; q < 8; ++q) {
    int r = 8 * w + q;
    float pe = pos_emb[r * 64 + lane];
    h0[q] = tok_emb[toks[r] * 64 + lane]      + pe;
    h1[q] = tok_emb[toks[32 + r] * 64 + lane] + pe;
  }

  // LN both samples with one weight load; interleaved shuffles for ILP.
  auto layernorm2 = [&](const float* gp, const float* bp) {
    float gv = gp[lane], bv = bp[lane];
    float va[8], vb[8];
    #pragma unroll
    for (int q = 0; q < 8; ++q) {
      float sa = h0[q], qa_ = h0[q] * h0[q];
      float sb = h1[q], qb_ = h1[q] * h1[q];
      #pragma unroll
      for (int off = 32; off; off >>= 1) {
        sa  += __shfl_xor(sa, off);
        qa_ += __shfl_xor(qa_, off);
        sb  += __shfl_xor(sb, off);
        qb_ += __shfl_xor(qb_, off);
      }
      float ma = sa * 0.015625f, mb = sb * 0.015625f;
      float ra = rsqrtf(fmaf(-ma, ma, qa_ * 0.015625f) + 1e-5f);
      float rb = rsqrtf(fmaf(-mb, mb, qb_ * 0.015625f) + 1e-5f);
      va[q] = fmaf((h0[q] - ma) * ra, gv, bv);
      vb[q] = fmaf((h1[q] - mb) * rb, gv, bv);
    }
    *reinterpret_cast<float4*>(&SA0[lane * STR + 8 * w])     = make_float4(va[0], va[1], va[2], va[3]);
    *reinterpret_cast<float4*>(&SA0[lane * STR + 8 * w + 4]) = make_float4(va[4], va[5], va[6], va[7]);
    *reinterpret_cast<float4*>(&SA1[lane * STR + 8 * w])     = make_float4(vb[0], vb[1], vb[2], vb[3]);
    *reinterpret_cast<float4*>(&SA1[lane * STR + 8 * w + 4]) = make_float4(vb[4], vb[5], vb[6], vb[7]);
  };

  for (int l = 0; l < 6; ++l) {
    // ---------------- attention ----------------
    layernorm2(ln1_g + l * 64, ln1_b + l * 64);
    __syncthreads();   // (A) aT read cross-wave next

    const float* wl = wqkv + l * 64 * 192;
    const float* bq = bqkv + l * 192;
    float qa0[8], qa1[8];
    #pragma unroll
    for (int e = 0; e < 8; ++e) { qa0[e] = bq[8 * hh + e]; qa1[e] = qa0[e]; }
    float kb = bq[64 + lane], vb = bq[128 + lane];
    float k0a[8], k1a[8], v0a[8], v1a[8];
    #pragma unroll
    for (int q = 0; q < 8; ++q) { k0a[q] = kb; k1a[q] = kb; v0a[q] = vb; v1a[q] = vb; }

    // q: row-mode (broadcast weights, shared across samples).
    // k,v: column-mode (coalesced dword weights; wave-uniform LDS b128).
    #pragma unroll 2
    for (int d = 0; d < 64; ++d) {
      const float* wr = wl + d * 192;
      float4 wq0 = ld4(wr + 8 * hh);
      float4 wq1 = ld4(wr + 8 * hh + 4);
      float  wk  = wr[64 + lane];
      float  wv  = wr[128 + lane];
      float  av0 = SA0[d * STR + i32];
      float  av1 = SA1[d * STR + i32];
      float4 a0l = ld4(&SA0[d * STR + 8 * w]);
      float4 a0h = ld4(&SA0[d * STR + 8 * w + 4]);
      float4 a1l = ld4(&SA1[d * STR + 8 * w]);
      float4 a1h = ld4(&SA1[d * STR + 8 * w + 4]);
      fma8(qa0, wq0, wq1, av0);
      fma8(qa1, wq0, wq1, av1);
      fma8(k0a, a0l, a0h, wk);
      fma8(k1a, a1l, a1h, wk);
      fma8(v0a, a0l, a0h, wv);
      fma8(v1a, a1l, a1h, wv);
    }
    // fold softmax scale into q
    #pragma unroll
    for (int e = 0; e < 8; ++e) {
      qa0[e] *= 0.35355339059327373f;
      qa1[e] *= 0.35355339059327373f;
    }
    __syncthreads();   // (B) all aT reads done; SA may be overwritten

    // stage kT -> SA (over aT), vT -> SB; layout [channel][row]
    *reinterpret_cast<float4*>(&SA0[lane * STR + 8 * w])     = make_float4(k0a[0], k0a[1], k0a[2], k0a[3]);
    *reinterpret_cast<float4*>(&SA0[lane * STR + 8 * w + 4]) = make_float4(k0a[4], k0a[5], k0a[6], k0a[7]);
    *reinterpret_cast<float4*>(&SA1[lane * STR + 8 * w])     = make_float4(k1a[0], k1a[1], k1a[2], k1a[3]);
    *reinterpret_cast<float4*>(&SA1[lane * STR + 8 * w + 4]) = make_float4(k1a[4], k1a[5], k1a[6], k1a[7]);
    *reinterpret_cast<float4*>(&SB0[lane * STR + 8 * w])     = make_float4(v0a[0], v0a[1], v0a[2], v0a[3]);
    *reinterpret_cast<float4*>(&SB0[lane * STR + 8 * w + 4]) = make_float4(v0a[4], v0a[5], v0a[6], v0a[7]);
    *reinterpret_cast<float4*>(&SB1[lane * STR + 8 * w])     = make_float4(v1a[0], v1a[1], v1a[2], v1a[3]);
    *reinterpret_cast<float4*>(&SB1[lane * STR + 8 * w + 4]) = make_float4(v1a[4], v1a[5], v1a[6], v1a[7]);
    __syncthreads();   // (B2) kT/vT visible cross-wave

    // scores/softmax/o per sample (p[32] reused); thread = (row i32, head hh)
    float oa0[8], oa1[8];
    #pragma unroll
    for (int t = 0; t < 2; ++t) {
      const float* KT = t ? SA1 : SA0;
      const float* VT = t ? SB1 : SB0;
      const float* qa = t ? qa1 : qa0;
      float p[32];
      #pragma unroll
      for (int j4 = 0; j4 < 8; ++j4) {
        float a0 = 0.f, a1 = 0.f, a2 = 0.f, a3 = 0.f;
        #pragma unroll
        for (int c = 0; c < 8; ++c) {
          float4 kv = ld4(&KT[(8 * hh + c) * STR + 4 * j4]);
          a0 = fmaf(qa[c], kv.x, a0);
          a1 = fmaf(qa[c], kv.y, a1);
          a2 = fmaf(qa[c], kv.z, a2);
          a3 = fmaf(qa[c], kv.w, a3);
        }
        p[4 * j4]     = a0;
        p[4 * j4 + 1] = a1;
        p[4 * j4 + 2] = a2;
        p[4 * j4 + 3] = a3;
      }
      float mx = NEGV;
      #pragma unroll
      for (int j = 0; j < 32; ++j) {
        p[j] = (j <= i32) ? p[j] : NEGV;
        mx = fmaxf(mx, p[j]);
      }
      float sum = 0.f;
      #pragma unroll
      for (int j = 0; j < 32; ++j) {
        p[j] = __expf(p[j] - mx);
        sum += p[j];
      }
      float inv = 1.0f / sum;
      #pragma unroll
      for (int j = 0; j < 32; ++j) p[j] *= inv;

      float* oa = t ? oa1 : oa0;
      #pragma unroll
      for (int e = 0; e < 8; ++e) {
        float acc = 0.f;
        #pragma unroll
        for (int j4 = 0; j4 < 8; ++j4) {
          float4 vv = ld4(&VT[(8 * hh + e) * STR + 4 * j4]);
          acc = fmaf(p[4 * j4],     vv.x, acc);
          acc = fmaf(p[4 * j4 + 1], vv.y, acc);
          acc = fmaf(p[4 * j4 + 2], vv.z, acc);
          acc = fmaf(p[4 * j4 + 3], vv.w, acc);
        }
        oa[e] = acc;
      }
    }
    // oT -> SA over own head's kT rows (same half-wave; in-order, no barrier)
    #pragma unroll
    for (int e = 0; e < 8; ++e) {
      SA0[(8 * hh + e) * STR + i32] = oa0[e];
      SA1[(8 * hh + e) * STR + i32] = oa1[e];
    }
    __syncthreads();   // (C) oT read cross-wave next

    // h += oT * wo  (own 8 rows, both samples; one weight load per d)
    const float* wop = wo + l * 4096 + lane;
    #pragma unroll 2
    for (int d = 0; d < 64; ++d) {
      float wv = wop[d * 64];
      float4 o0l = ld4(&SA0[d * STR + 8 * w]);
      float4 o0h = ld4(&SA0[d * STR + 8 * w + 4]);
      float4 o1l = ld4(&SA1[d * STR + 8 * w]);
      float4 o1h = ld4(&SA1[d * STR + 8 * w + 4]);
      fma8(h0, o0l, o0h, wv);
      fma8(h1, o1l, o1h, wv);
    }
    {
      float bov = bo[l * 64 + lane];
      #pragma unroll
      for (int q = 0; q < 8; ++q) { h0[q] += bov; h1[q] += bov; }
    }
    // no barrier: wo reads + LN2 writes touch the same own-wave region

    // ---------------- MLP (no internal barriers; own-wave traffic) ----------
    layernorm2(ln2_g + l * 64, ln2_b + l * 64);
    const float* w1base = w1 + l * 64 * 256;
    const float* w2base = w2 + l * 256 * 64;
    for (int cc = 0; cc < 4; ++cc) {
      float b1v = b1[l * 256 + cc * 64 + lane];
      float m0[8], m1v[8];
      #pragma unroll
      for (int q = 0; q < 8; ++q) { m0[q] = b1v; m1v[q] = b1v; }
      const float* w1p = w1base + cc * 64 + lane;
      #pragma unroll 2
      for (int d = 0; d < 64; ++d) {
        float wv = w1p[d * 256];
        float4 a0l = ld4(&SA0[d * STR + 8 * w]);
        float4 a0h = ld4(&SA0[d * STR + 8 * w + 4]);
        float4 a1l = ld4(&SA1[d * STR + 8 * w]);
        float4 a1h = ld4(&SA1[d * STR + 8 * w + 4]);
        fma8(m0,  a0l, a0h, wv);
        fma8(m1v, a1l, a1h, wv);
      }
      // m1T -> SB own cols (overwrites vT / prev m1T; vT last read pre-(C))
      *reinterpret_cast<float4*>(&SB0[lane * STR + 8 * w]) =
          make_float4(fmaxf(m0[0], 0.f), fmaxf(m0[1], 0.f),
                      fmaxf(m0[2], 0.f), fmaxf(m0[3], 0.f));
      *reinterpret_cast<float4*>(&SB0[lane * STR + 8 * w + 4]) =
          make_float4(fmaxf(m0[4], 0.f), fmaxf(m0[5], 0.f),
                      fmaxf(m0[6], 0.f), fmaxf(m0[7], 0.f));
      *reinterpret_cast<float4*>(&SB1[lane * STR + 8 * w]) =
          make_float4(fmaxf(m1v[0], 0.f), fmaxf(m1v[1], 0.f),
                      fmaxf(m1v[2], 0.f), fmaxf(m1v[3], 0.f));
      *reinterpret_cast<float4*>(&SB1[lane * STR + 8 * w + 4]) =
          make_float4(fmaxf(m1v[4], 0.f), fmaxf(m1v[5], 0.f),
                      fmaxf(m1v[6], 0.f), fmaxf(m1v[7], 0.f));
      const float* w2p = w2base + cc * 64 * 64 + lane;
      #pragma unroll 2
      for (int dc = 0; dc < 64; ++dc) {
        float wv = w2p[dc * 64];
        float4 q0l = ld4(&SB0[dc * STR + 8 * w]);
        float4 q0h = ld4(&SB0[dc * STR + 8 * w + 4]);
        float4 q1l = ld4(&SB1[dc * STR + 8 * w]);
        float4 q1h = ld4(&SB1[dc * STR + 8 * w + 4]);
        fma8(h0, q0l, q0h, wv);
        fma8(h1, q1l, q1h, wv);
      }
    }
    {
      float b2v = b2[l * 64 + lane];
      #pragma unroll
      for (int q = 0; q < 8; ++q) { h0[q] += b2v; h1[q] += b2v; }
    }
  }

  // ---------------- head: wave 0 -> sample 0, wave 1 -> sample 1 ------------
  layernorm2(lnf_g, lnf_b);
  __syncthreads();   // cross-wave logits reads

  if (w < 2) {
    const float* SAt = w ? SA1 : SA0;
    float la = b_out[2 * g], lb = b_out[2 * g + 1];
    #pragma unroll 4
    for (int d = 0; d < 64; ++d) {
      float av = SAt[d * STR + i32];
      la = fmaf(av, w_out[d * 4 + 2 * g],     la);
      lb = fmaf(av, w_out[d * 4 + 2 * g + 1], lb);
    }
    float lc  = __shfl_xor(la, 32);
    float ldt = __shfl_xor(lb, 32);

    int r   = i32;
    int nup = __popcll(um & ((1ull << r) - 1ull));
    int ndn = __popcll(dm & ((1ull << r) - 1ull));
    int rem = 31 - r;
    float lg[4] = {la, lb, lc, ldt};   // valid on lanes<32 (g=0)
    float ml[4];
    #pragma unroll
    for (int c = 0; c < 4; ++c) {
      int nu = nup + (c & 1);
      int nd = ndn + (c >> 1);
      bool ok = (nu <= 16) && (nd <= 16) && (16 - nu <= rem) && (16 - nd <= rem);
      ml[c] = ok ? lg[c] : NEGV;
    }
    float m4 = fmaxf(fmaxf(ml[0], ml[1]), fmaxf(ml[2], ml[3]));
    float se = __expf(ml[0] - m4) + __expf(ml[1] - m4) +
               __expf(ml[2] - m4) + __expf(ml[3] - m4);
    int c = pis[32 * w + r];
    float mls = (c == 0) ? ml[0] : (c == 1) ? ml[1] : (c == 2) ? ml[2] : ml[3];
    float amps = (lane < 32) ? (mls - m4 - __logf(se)) : 0.f;
    #pragma unroll
    for (int off = 32; off; off >>= 1) amps += __shfl_xor(amps, off);

    // phase MLP for own sample (in-wave LDS ordering; no barrier)
    const float* xst = xs + 64 * w;
    float p1 = bp1[lane];
    #pragma unroll 4
    for (int d = 0; d < 64; ++d)
      p1 = fmaf(xst[d], wp1[d * 64 + lane], p1);
    p1 = fmaxf(p1, 0.f);
    phb[64 * w + lane] = p1;
    float p2 = bp2[lane];
    #pragma unroll 4
    for (int d = 0; d < 64; ++d)
      p2 = fmaf(phb[64 * w + d], wp2[d * 64 + lane], p2);
    p2 = fmaxf(p2, 0.f);
    float p3 = p2 * wp3[lane];
    #pragma unroll
    for (int off = 32; off; off >>= 1) p3 += __shfl_xor(p3, off);
    float ph = p3 + bp3[0];

    if (lane == 0 && (w == 0 || valid1)) {
      int S = 2 * s2 + w;
      float amp = expf(0.5f * amps);
      if (out_pairs) {
        out[2 * S]     = amp * cosf(ph);
        out[2 * S + 1] = amp * sinf(ph);
      } else {
        // harness flattened complex64 via astype(float32): real part only
        out[S] = amp * cosf(ph);
      }
    }
  }
}

extern "C" void kernel_launch(void* const* d_in, const int* in_sizes, int n_in,
                              void* d_out, int out_size, void* d_ws, size_t ws_size,
                              hipStream_t stream) {
  (void)n_in; (void)d_ws; (void)ws_size;
  const int B = in_sizes[0] / 64;
  const int out_pairs = (out_size >= 2 * B) ? 1 : 0;
  const int grid = (B + 1) / 2;
  dwf_kernel<<<grid, 256, 0, stream>>>(
      (const float*)d_in[0],  (const float*)d_in[1],  (const float*)d_in[2],
      (const float*)d_in[3],  (const float*)d_in[4],  (const float*)d_in[5],
      (const float*)d_in[6],  (const float*)d_in[7],  (const float*)d_in[8],
      (const float*)d_in[9],  (const float*)d_in[10], (const float*)d_in[11],
      (const float*)d_in[12], (const float*)d_in[13], (const float*)d_in[14],
      (const float*)d_in[15], (const float*)d_in[16], (const float*)d_in[17],
      (const float*)d_in[18], (const float*)d_in[19], (const float*)d_in[20],
      (const float*)d_in[21], (const float*)d_in[22], (const float*)d_in[23],
      (const float*)d_in[24], (float*)d_out, out_pairs, B);
}